// Round 4
// baseline (534.737 us; speedup 1.0000x reference)
//
#include <hip/hip_runtime.h>

typedef unsigned short u16;
typedef unsigned int u32;
typedef __bf16 bf16_t;
typedef __attribute__((ext_vector_type(8))) bf16_t bf16x8;
typedef __attribute__((ext_vector_type(4))) float f32x4;

__device__ inline u16 f2bf(float f) {
    union { float f; u32 u; } v; v.f = f;
    u32 u = v.u;
    u32 r = (u + 0x7fffu + ((u >> 16) & 1u)) >> 16;
    return (u16)r;
}

// async global->LDS, 16B per lane; LDS dest is wave-uniform base + lane*16
__device__ inline void async_cp16(const void* g, void* l) {
    __builtin_amdgcn_global_load_lds((const __attribute__((address_space(1))) void*)g,
                                     (__attribute__((address_space(3))) void*)l, 16, 0, 0);
}

// ---------------- fp32 -> bf16 convert, 3 arrays fused ----------------
__global__ __launch_bounds__(256) void cvt3(const float* __restrict__ a,
                                            const float* __restrict__ b,
                                            const float* __restrict__ c,
                                            u16* __restrict__ oa, u16* __restrict__ ob,
                                            u16* __restrict__ oc) {
    int z = blockIdx.y;
    const float* in = z == 0 ? a : (z == 1 ? b : c);
    u16* out = z == 0 ? oa : (z == 1 ? ob : oc);
    int i = (blockIdx.x * 256 + threadIdx.x) * 4;
    float4 f = *(const float4*)(in + i);
    ushort4 o;
    o.x = f2bf(f.x); o.y = f2bf(f.y); o.z = f2bf(f.z); o.w = f2bf(f.w);
    *(ushort4*)(out + i) = o;
}

// ---------------- W[K][N] fp32 -> WT[N][K] bf16, 2 matrices fused ----------------
__global__ __launch_bounds__(256) void transpose2(const float* __restrict__ W0,
                                                  u16* __restrict__ T0,
                                                  const float* __restrict__ W1,
                                                  u16* __restrict__ T1,
                                                  int K, int N) {
    const float* W = blockIdx.z == 0 ? W0 : W1;
    u16* WT = blockIdx.z == 0 ? T0 : T1;
    __shared__ float tile[32][33];
    int tr0 = blockIdx.x * 32;
    int tc0 = blockIdx.y * 32;
    int t = threadIdx.x;
    for (int i = 0; i < 4; i++) {
        int idx = t + i * 256; int r = idx >> 5, c = idx & 31;
        tile[r][c] = W[(size_t)(tr0 + r) * N + tc0 + c];
    }
    __syncthreads();
    for (int i = 0; i < 4; i++) {
        int idx = t + i * 256; int r = idx >> 5, c = idx & 31;
        WT[(size_t)(tc0 + r) * K + tr0 + c] = f2bf(tile[c][r]);
    }
}

// ---------------- C = A[M][K] * BT[N][K]^T + bias, m97-pattern staging ----------------
template <typename OUT_T>
__global__ __launch_bounds__(256) void gemm_bt(const u16* __restrict__ A,
                                               const u16* __restrict__ BT,
                                               const float* __restrict__ bias,
                                               OUT_T* __restrict__ C,
                                               int M, int N, int K, int ldout) {
    __shared__ u16 sA[128 * 32];
    __shared__ u16 sB[128 * 32];
    int t = threadIdx.x, lane = t & 63, wv = t >> 6;
    int quad = lane >> 4, c16 = lane & 15;
    int bm = blockIdx.x * 128, bn = blockIdx.y * 128;
    int wm = (wv & 1) * 64, wn = (wv >> 1) * 64;
    f32x4 acc[4][4] = {};

    int srow = wv * 32 + (lane >> 2);
    int scol = (lane & 3) * 8;
    const u16* Ag = A + (size_t)(bm + srow) * K + scol;
    const u16* Bg = BT + (size_t)(bn + srow) * K + scol;
    u16* sAd = &sA[(wv * 32) * 32];
    u16* sBd = &sB[(wv * 32) * 32];

    for (int k0 = 0; k0 < K; k0 += 32) {
        __syncthreads();
        async_cp16(Ag + k0, sAd);
        async_cp16(Ag + (size_t)16 * K + k0, sAd + 16 * 32);
        async_cp16(Bg + k0, sBd);
        async_cp16(Bg + (size_t)16 * K + k0, sBd + 16 * 32);
        __syncthreads();
        bf16x8 af[4], bfr[4];
        for (int mi = 0; mi < 4; mi++)
            af[mi] = *(const bf16x8*)&sA[(wm + mi * 16 + c16) * 32 + quad * 8];
        for (int ni = 0; ni < 4; ni++)
            bfr[ni] = *(const bf16x8*)&sB[(wn + ni * 16 + c16) * 32 + quad * 8];
        for (int mi = 0; mi < 4; mi++)
            for (int ni = 0; ni < 4; ni++)
                acc[mi][ni] = __builtin_amdgcn_mfma_f32_16x16x32_bf16(
                    af[mi], bfr[ni], acc[mi][ni], 0, 0, 0);
    }

    for (int mi = 0; mi < 4; mi++) {
        for (int ni = 0; ni < 4; ni++) {
            int col = bn + wn + ni * 16 + c16;
            float bv = bias[col];
            for (int p = 0; p < 4; p++) {
                int row = bm + wm + mi * 16 + quad * 4 + p;
                float v = acc[mi][ni][p] + bv;
                size_t off = (size_t)row * ldout + col;
                if constexpr (__is_same(OUT_T, u16)) C[off] = f2bf(v);
                else C[off] = v;
            }
        }
    }
}

// ---------------- K/V projection, split-K with fp32 atomic partials ----------------
// grid (M/128, 2 {k,v}, NSPLIT); each block does K-range [z*KS, (z+1)*KS)
__global__ __launch_bounds__(256) void gemm_kv_sk(const u16* __restrict__ kbf,
                                                  const u16* __restrict__ vbf,
                                                  const u16* __restrict__ WkT,
                                                  const u16* __restrict__ WvT,
                                                  float* __restrict__ kacc,
                                                  float* __restrict__ vacc,
                                                  int K, int KS) {
    bool isv = blockIdx.y == 1;
    const u16* A = isv ? vbf : kbf;
    const u16* BT = isv ? WvT : WkT;
    float* aco = isv ? vacc : kacc;
    __shared__ u16 sA[128 * 32];
    __shared__ u16 sB[128 * 32];
    int t = threadIdx.x, lane = t & 63, wv = t >> 6;
    int quad = lane >> 4, c16 = lane & 15;
    int bm = blockIdx.x * 128;
    int wm = (wv & 1) * 64, wn = (wv >> 1) * 64;
    f32x4 acc[4][4] = {};

    int srow = wv * 32 + (lane >> 2);
    int scol = (lane & 3) * 8;
    const u16* Ag = A + (size_t)(bm + srow) * K + scol;
    const u16* Bg = BT + (size_t)srow * K + scol;
    u16* sAd = &sA[(wv * 32) * 32];
    u16* sBd = &sB[(wv * 32) * 32];

    int kbeg = blockIdx.z * KS;
    for (int k0 = kbeg; k0 < kbeg + KS; k0 += 32) {
        __syncthreads();
        async_cp16(Ag + k0, sAd);
        async_cp16(Ag + (size_t)16 * K + k0, sAd + 16 * 32);
        async_cp16(Bg + k0, sBd);
        async_cp16(Bg + (size_t)16 * K + k0, sBd + 16 * 32);
        __syncthreads();
        bf16x8 af[4], bfr[4];
        for (int mi = 0; mi < 4; mi++)
            af[mi] = *(const bf16x8*)&sA[(wm + mi * 16 + c16) * 32 + quad * 8];
        for (int ni = 0; ni < 4; ni++)
            bfr[ni] = *(const bf16x8*)&sB[(wn + ni * 16 + c16) * 32 + quad * 8];
        for (int mi = 0; mi < 4; mi++)
            for (int ni = 0; ni < 4; ni++)
                acc[mi][ni] = __builtin_amdgcn_mfma_f32_16x16x32_bf16(
                    af[mi], bfr[ni], acc[mi][ni], 0, 0, 0);
    }

    for (int mi = 0; mi < 4; mi++)
        for (int ni = 0; ni < 4; ni++) {
            int col = wn + ni * 16 + c16;
            for (int p = 0; p < 4; p++) {
                int row = bm + wm + mi * 16 + quad * 4 + p;
                atomicAdd(&aco[(size_t)row * 128 + col], acc[mi][ni][p]);
            }
        }
}

// ---------------- kv epilogue: +bias, ->bf16; z=0: khb copy; z=1: vhT transpose ----------------
__global__ __launch_bounds__(256) void cvt_kv(const float* __restrict__ kacc,
                                              const float* __restrict__ vacc,
                                              const float* __restrict__ bk,
                                              const float* __restrict__ bv,
                                              u16* __restrict__ khb,
                                              u16* __restrict__ vhT,
                                              int M) {
    int t = threadIdx.x;
    int tr0 = blockIdx.x * 32;  // row in M
    int tc0 = blockIdx.y * 32;  // col in 128
    if (blockIdx.z == 0) {
        // khb[row][col] = kacc + bk, coalesced
        for (int i = 0; i < 4; i++) {
            int idx = t + i * 256; int r = idx >> 5, c = idx & 31;
            khb[(size_t)(tr0 + r) * 128 + tc0 + c] =
                f2bf(kacc[(size_t)(tr0 + r) * 128 + tc0 + c] + bk[tc0 + c]);
        }
    } else {
        __shared__ float tile[32][33];
        for (int i = 0; i < 4; i++) {
            int idx = t + i * 256; int r = idx >> 5, c = idx & 31;
            tile[r][c] = vacc[(size_t)(tr0 + r) * 128 + tc0 + c] + bv[tc0 + c];
        }
        __syncthreads();
        for (int i = 0; i < 4; i++) {
            int idx = t + i * 256; int r = idx >> 5, c = idx & 31;
            vhT[(size_t)(tc0 + r) * M + tr0 + c] = f2bf(tile[c][r]);
        }
    }
}

// ---------------- flash attention v4: 64 q-rows per wave, 2-wave blocks ----------------
// Block: 128 threads = 2 waves, 128 Q rows of one (b,h); wave owns 64 rows (4x16).
// kv tile = 64. Transposed scores + static softmax (round-3 scheme), per-16kv-strip fusion.
__global__ __launch_bounds__(128) void mqa_attn(const u16* __restrict__ qh,   // [B*S][2048]
                                                const u16* __restrict__ kh,   // [B*S][128]
                                                const u16* __restrict__ vhT,  // [128][B*S]
                                                u16* __restrict__ outp,       // [B*S][2048]
                                                int S) {
    constexpr float CEXP = 0.08838834764831845f * 1.4426950408889634f;  // scale * log2(e)
    constexpr int KSTR = 136;  // u16 elems
    constexpr int VSTR = 72;
    constexpr int PSTR = 72;
    __shared__ u16 sK[64 * KSTR];        // 17408 B
    __shared__ u16 sVT[128 * VSTR];      // 18432 B
    __shared__ u16 sP[2 * 64 * PSTR];    // 18432 B  (per-wave 64 q-rows)

    int t = threadIdx.x, lane = t & 63, wv = t >> 6;
    int quad = lane >> 4, c16 = lane & 15;
    int b = blockIdx.z, h = blockIdx.y;
    int q0 = blockIdx.x * 128 + wv * 64;
    int BS = b * S;

    // Q fragments (B-operand of S^T mfma): rows q0 + mi*16 + c16
    bf16x8 aq[4][4];
    for (int mi = 0; mi < 4; mi++) {
        const u16* qp = qh + (size_t)(BS + q0 + mi * 16 + c16) * 2048 + h * 128 + quad * 8;
        for (int c = 0; c < 4; c++) aq[mi][c] = *(const bf16x8*)(qp + c * 32);
    }

    f32x4 out[4][8] = {};
    f32x4 lsumv[4] = {};
    u16* sPw = sP + wv * (64 * PSTR);

    // staging coords (128 threads): K 64x128, VT 128x64
    int kr = t >> 4, kc = (t & 15) * 8;   // 8 rows x 16 chunks per pass, 8 passes
    int vr = t >> 3, vc = (t & 7) * 8;    // 16 rows x 8 chunks per pass, 8 passes
    const u16* kbase = kh + (size_t)(BS + kr) * 128 + kc;
    const u16* vbase = vhT + (size_t)vr * 4096 + BS + vc;

    for (int kv0 = 0; kv0 < S; kv0 += 64) {
        __syncthreads();
        for (int ps = 0; ps < 8; ps++)
            *(uint4*)&sK[(kr + ps * 8) * KSTR + kc] =
                *(const uint4*)(kbase + (size_t)(kv0 + ps * 8) * 128);
        for (int ps = 0; ps < 8; ps++)
            *(uint4*)&sVT[(vr + ps * 16) * VSTR + vc] =
                *(const uint4*)(vbase + (size_t)(ps * 16) * 4096 + kv0);
        __syncthreads();

        // score strips: 16 kv rows at a time; S^T = K*Q^T (D: row=kv, col=q)
        for (int ni = 0; ni < 4; ni++) {
            f32x4 sc[4] = {};
            for (int c = 0; c < 4; c++) {
                bf16x8 bk = *(const bf16x8*)&sK[(ni * 16 + c16) * KSTR + quad * 8 + c * 32];
                for (int mi = 0; mi < 4; mi++)
                    sc[mi] = __builtin_amdgcn_mfma_f32_16x16x32_bf16(bk, aq[mi][c], sc[mi], 0, 0, 0);
            }
            // static softmax; l summed from truncated bf16 so bias cancels in PV/l
            for (int mi = 0; mi < 4; mi++) {
                u32 eu[4];
                f32x4 et;
                for (int p = 0; p < 4; p++) {
                    float e = __builtin_amdgcn_exp2f(sc[mi][p] * CEXP);
                    union { float f; u32 u; } cv; cv.f = e;
                    eu[p] = cv.u;
                    cv.u &= 0xffff0000u;
                    et[p] = cv.f;
                }
                lsumv[mi] += et;
                u32 pk0 = __builtin_amdgcn_perm(eu[1], eu[0], 0x07060302u);
                u32 pk1 = __builtin_amdgcn_perm(eu[3], eu[2], 0x07060302u);
                *(uint2*)&sPw[(mi * 16 + c16) * PSTR + ni * 16 + quad * 4] = make_uint2(pk0, pk1);
            }
        }
        asm volatile("s_waitcnt lgkmcnt(0)" ::: "memory");

        // PV: O += P[64 x 64] * V[64 x 128]
        bf16x8 ap[4][2];
        for (int mi = 0; mi < 4; mi++) {
            ap[mi][0] = *(const bf16x8*)&sPw[(mi * 16 + c16) * PSTR + quad * 8];
            ap[mi][1] = *(const bf16x8*)&sPw[(mi * 16 + c16) * PSTR + quad * 8 + 32];
        }
        for (int ni = 0; ni < 8; ni++) {
            bf16x8 bv0 = *(const bf16x8*)&sVT[(ni * 16 + c16) * VSTR + quad * 8];
            bf16x8 bv1 = *(const bf16x8*)&sVT[(ni * 16 + c16) * VSTR + quad * 8 + 32];
            for (int mi = 0; mi < 4; mi++) {
                out[mi][ni] = __builtin_amdgcn_mfma_f32_16x16x32_bf16(ap[mi][0], bv0, out[mi][ni], 0, 0, 0);
                out[mi][ni] = __builtin_amdgcn_mfma_f32_16x16x32_bf16(ap[mi][1], bv1, out[mi][ni], 0, 0, 0);
            }
        }
    }

    // epilogue: reduce l across quad-groups, redistribute by q-row, scale, store
    for (int mi = 0; mi < 4; mi++) {
        float lp = lsumv[mi][0] + lsumv[mi][1] + lsumv[mi][2] + lsumv[mi][3];
        lp += __shfl_xor(lp, 16, 64);
        lp += __shfl_xor(lp, 32, 64);  // all lanes: l(q = mi*16 + c16)
        float inv[4];
        for (int p = 0; p < 4; p++)
            inv[p] = 1.f / __shfl(lp, quad * 4 + p, 64);
        u16* op = outp + (size_t)(BS + q0 + mi * 16 + quad * 4) * 2048 + h * 128;
        for (int ni = 0; ni < 8; ni++)
            for (int p = 0; p < 4; p++)
                op[(size_t)p * 2048 + ni * 16 + c16] = f2bf(out[mi][ni][p] * inv[p]);
    }
}

extern "C" void kernel_launch(void* const* d_in, const int* in_sizes, int n_in,
                              void* d_out, int out_size, void* d_ws, size_t ws_size,
                              hipStream_t stream) {
    const float* q  = (const float*)d_in[0];
    const float* k  = (const float*)d_in[1];
    const float* v  = (const float*)d_in[2];
    const float* Wq = (const float*)d_in[3];
    const float* bq = (const float*)d_in[4];
    const float* Wk = (const float*)d_in[5];
    const float* bk = (const float*)d_in[6];
    const float* Wv = (const float*)d_in[7];
    const float* bv = (const float*)d_in[8];
    const float* Wo = (const float*)d_in[9];
    const float* bo = (const float*)d_in[10];
    float* out = (float*)d_out;

    const int S = 2048, D = 2048, Dh = 128, M = 4096;  // M = B*S
    const int QKV = M * D;
    const int WDD = D * D;
    const int WDH = D * Dh;
    const int MDh = M * Dh;

    u16* ws   = (u16*)d_ws;
    u16* q_bf = ws;
    u16* k_bf = q_bf + QKV;
    u16* v_bf = k_bf + QKV;
    u16* WqT  = v_bf + QKV;
    u16* WoT  = WqT + WDD;
    u16* WkT  = WoT + WDD;
    u16* WvT  = WkT + WDH;
    u16* qhb  = WvT + WDH;       // [M][2048] bf16
    u16* khb  = qhb + QKV;       // [M][128]
    u16* vhTb = khb + MDh;       // [128][M]
    u16* aout = vhTb + MDh;      // [M][2048]
    float* kacc = (float*)(aout + QKV);  // [M][128] fp32
    float* vacc = kacc + MDh;            // [M][128] fp32

    hipMemsetAsync(kacc, 0, (size_t)2 * MDh * sizeof(float), stream);

    cvt3<<<dim3(QKV / 1024, 3), 256, 0, stream>>>(q, k, v, q_bf, k_bf, v_bf);
    transpose2<<<dim3(64, 64, 2), 256, 0, stream>>>(Wq, WqT, Wo, WoT, D, D);
    transpose2<<<dim3(64, 4, 2), 256, 0, stream>>>(Wk, WkT, Wv, WvT, D, Dh);

    gemm_bt<u16><<<dim3(32, 16), 256, 0, stream>>>(q_bf, WqT, bq, qhb, M, D, D, D);
    gemm_kv_sk<<<dim3(32, 2, 4), 256, 0, stream>>>(k_bf, v_bf, WkT, WvT, kacc, vacc, D, 512);
    cvt_kv<<<dim3(128, 4, 2), 256, 0, stream>>>(kacc, vacc, bk, bv, khb, vhTb, M);

    mqa_attn<<<dim3(16, 16, 2), 128, 0, stream>>>(qhb, khb, vhTb, aout, S);

    gemm_bt<float><<<dim3(32, 16), 256, 0, stream>>>(aout, WoT, bo, out, M, D, D, D);
}

// Round 5
// 435.252 us; speedup vs baseline: 1.2286x; 1.2286x over previous
//
#include <hip/hip_runtime.h>

typedef unsigned short u16;
typedef unsigned int u32;
typedef __bf16 bf16_t;
typedef __attribute__((ext_vector_type(8))) bf16_t bf16x8;
typedef __attribute__((ext_vector_type(4))) float f32x4;

__device__ inline u16 f2bf(float f) {
    union { float f; u32 u; } v; v.f = f;
    u32 u = v.u;
    u32 r = (u + 0x7fffu + ((u >> 16) & 1u)) >> 16;
    return (u16)r;
}

// async global->LDS, 16B per lane; LDS dest is wave-uniform base + lane*16
__device__ inline void async_cp16(const void* g, void* l) {
    __builtin_amdgcn_global_load_lds((const __attribute__((address_space(1))) void*)g,
                                     (__attribute__((address_space(3))) void*)l, 16, 0, 0);
}

// ---------------- fp32 -> bf16 convert, 3 arrays fused ----------------
__global__ __launch_bounds__(256) void cvt3(const float* __restrict__ a,
                                            const float* __restrict__ b,
                                            const float* __restrict__ c,
                                            u16* __restrict__ oa, u16* __restrict__ ob,
                                            u16* __restrict__ oc) {
    int z = blockIdx.y;
    const float* in = z == 0 ? a : (z == 1 ? b : c);
    u16* out = z == 0 ? oa : (z == 1 ? ob : oc);
    int i = (blockIdx.x * 256 + threadIdx.x) * 4;
    float4 f = *(const float4*)(in + i);
    ushort4 o;
    o.x = f2bf(f.x); o.y = f2bf(f.y); o.z = f2bf(f.z); o.w = f2bf(f.w);
    *(ushort4*)(out + i) = o;
}

// ---------------- W[K][N] fp32 -> WT[N][K] bf16, 2 matrices fused ----------------
__global__ __launch_bounds__(256) void transpose2(const float* __restrict__ W0,
                                                  u16* __restrict__ T0,
                                                  const float* __restrict__ W1,
                                                  u16* __restrict__ T1,
                                                  int K, int N) {
    const float* W = blockIdx.z == 0 ? W0 : W1;
    u16* WT = blockIdx.z == 0 ? T0 : T1;
    __shared__ float tile[32][33];
    int tr0 = blockIdx.x * 32;
    int tc0 = blockIdx.y * 32;
    int t = threadIdx.x;
    for (int i = 0; i < 4; i++) {
        int idx = t + i * 256; int r = idx >> 5, c = idx & 31;
        tile[r][c] = W[(size_t)(tr0 + r) * N + tc0 + c];
    }
    __syncthreads();
    for (int i = 0; i < 4; i++) {
        int idx = t + i * 256; int r = idx >> 5, c = idx & 31;
        WT[(size_t)(tc0 + r) * K + tr0 + c] = f2bf(tile[c][r]);
    }
}

// ---------------- C = A[M][K] * BT[N][K]^T + bias, m97-pattern staging ----------------
template <typename OUT_T>
__global__ __launch_bounds__(256) void gemm_bt(const u16* __restrict__ A,
                                               const u16* __restrict__ BT,
                                               const float* __restrict__ bias,
                                               OUT_T* __restrict__ C,
                                               int M, int N, int K, int ldout) {
    __shared__ u16 sA[128 * 32];
    __shared__ u16 sB[128 * 32];
    int t = threadIdx.x, lane = t & 63, wv = t >> 6;
    int quad = lane >> 4, c16 = lane & 15;
    int bm = blockIdx.x * 128, bn = blockIdx.y * 128;
    int wm = (wv & 1) * 64, wn = (wv >> 1) * 64;
    f32x4 acc[4][4] = {};

    int srow = wv * 32 + (lane >> 2);
    int scol = (lane & 3) * 8;
    const u16* Ag = A + (size_t)(bm + srow) * K + scol;
    const u16* Bg = BT + (size_t)(bn + srow) * K + scol;
    u16* sAd = &sA[(wv * 32) * 32];
    u16* sBd = &sB[(wv * 32) * 32];

    for (int k0 = 0; k0 < K; k0 += 32) {
        __syncthreads();
        async_cp16(Ag + k0, sAd);
        async_cp16(Ag + (size_t)16 * K + k0, sAd + 16 * 32);
        async_cp16(Bg + k0, sBd);
        async_cp16(Bg + (size_t)16 * K + k0, sBd + 16 * 32);
        __syncthreads();
        bf16x8 af[4], bfr[4];
        for (int mi = 0; mi < 4; mi++)
            af[mi] = *(const bf16x8*)&sA[(wm + mi * 16 + c16) * 32 + quad * 8];
        for (int ni = 0; ni < 4; ni++)
            bfr[ni] = *(const bf16x8*)&sB[(wn + ni * 16 + c16) * 32 + quad * 8];
        for (int mi = 0; mi < 4; mi++)
            for (int ni = 0; ni < 4; ni++)
                acc[mi][ni] = __builtin_amdgcn_mfma_f32_16x16x32_bf16(
                    af[mi], bfr[ni], acc[mi][ni], 0, 0, 0);
    }

    for (int mi = 0; mi < 4; mi++) {
        for (int ni = 0; ni < 4; ni++) {
            int col = bn + wn + ni * 16 + c16;
            float bv = bias[col];
            for (int p = 0; p < 4; p++) {
                int row = bm + wm + mi * 16 + quad * 4 + p;
                float v = acc[mi][ni][p] + bv;
                size_t off = (size_t)row * ldout + col;
                if constexpr (__is_same(OUT_T, u16)) C[off] = f2bf(v);
                else C[off] = v;
            }
        }
    }
}

// ---------------- K/V projection, split-K with fp32 atomic partials ----------------
__global__ __launch_bounds__(256) void gemm_kv_sk(const u16* __restrict__ kbf,
                                                  const u16* __restrict__ vbf,
                                                  const u16* __restrict__ WkT,
                                                  const u16* __restrict__ WvT,
                                                  float* __restrict__ kacc,
                                                  float* __restrict__ vacc,
                                                  int K, int KS) {
    bool isv = blockIdx.y == 1;
    const u16* A = isv ? vbf : kbf;
    const u16* BT = isv ? WvT : WkT;
    float* aco = isv ? vacc : kacc;
    __shared__ u16 sA[128 * 32];
    __shared__ u16 sB[128 * 32];
    int t = threadIdx.x, lane = t & 63, wv = t >> 6;
    int quad = lane >> 4, c16 = lane & 15;
    int bm = blockIdx.x * 128;
    int wm = (wv & 1) * 64, wn = (wv >> 1) * 64;
    f32x4 acc[4][4] = {};

    int srow = wv * 32 + (lane >> 2);
    int scol = (lane & 3) * 8;
    const u16* Ag = A + (size_t)(bm + srow) * K + scol;
    const u16* Bg = BT + (size_t)srow * K + scol;
    u16* sAd = &sA[(wv * 32) * 32];
    u16* sBd = &sB[(wv * 32) * 32];

    int kbeg = blockIdx.z * KS;
    for (int k0 = kbeg; k0 < kbeg + KS; k0 += 32) {
        __syncthreads();
        async_cp16(Ag + k0, sAd);
        async_cp16(Ag + (size_t)16 * K + k0, sAd + 16 * 32);
        async_cp16(Bg + k0, sBd);
        async_cp16(Bg + (size_t)16 * K + k0, sBd + 16 * 32);
        __syncthreads();
        bf16x8 af[4], bfr[4];
        for (int mi = 0; mi < 4; mi++)
            af[mi] = *(const bf16x8*)&sA[(wm + mi * 16 + c16) * 32 + quad * 8];
        for (int ni = 0; ni < 4; ni++)
            bfr[ni] = *(const bf16x8*)&sB[(wn + ni * 16 + c16) * 32 + quad * 8];
        for (int mi = 0; mi < 4; mi++)
            for (int ni = 0; ni < 4; ni++)
                acc[mi][ni] = __builtin_amdgcn_mfma_f32_16x16x32_bf16(
                    af[mi], bfr[ni], acc[mi][ni], 0, 0, 0);
    }

    for (int mi = 0; mi < 4; mi++)
        for (int ni = 0; ni < 4; ni++) {
            int col = wn + ni * 16 + c16;
            for (int p = 0; p < 4; p++) {
                int row = bm + wm + mi * 16 + quad * 4 + p;
                atomicAdd(&aco[(size_t)row * 128 + col], acc[mi][ni][p]);
            }
        }
}

// ---------------- kv epilogue: +bias, ->bf16; z=0: khb copy; z=1: vhT transpose ----------------
__global__ __launch_bounds__(256) void cvt_kv(const float* __restrict__ kacc,
                                              const float* __restrict__ vacc,
                                              const float* __restrict__ bk,
                                              const float* __restrict__ bv,
                                              u16* __restrict__ khb,
                                              u16* __restrict__ vhT,
                                              int M) {
    int t = threadIdx.x;
    int tr0 = blockIdx.x * 32;
    int tc0 = blockIdx.y * 32;
    if (blockIdx.z == 0) {
        for (int i = 0; i < 4; i++) {
            int idx = t + i * 256; int r = idx >> 5, c = idx & 31;
            khb[(size_t)(tr0 + r) * 128 + tc0 + c] =
                f2bf(kacc[(size_t)(tr0 + r) * 128 + tc0 + c] + bk[tc0 + c]);
        }
    } else {
        __shared__ float tile[32][33];
        for (int i = 0; i < 4; i++) {
            int idx = t + i * 256; int r = idx >> 5, c = idx & 31;
            tile[r][c] = vacc[(size_t)(tr0 + r) * 128 + tc0 + c] + bv[tc0 + c];
        }
        __syncthreads();
        for (int i = 0; i < 4; i++) {
            int idx = t + i * 256; int r = idx >> 5, c = idx & 31;
            vhT[(size_t)(tc0 + r) * M + tr0 + c] = f2bf(tile[c][r]);
        }
    }
}

// ---------------- flash attention v5: 4 waves = (qhalf, kvhalf) ----------------
// Block: 256 threads, 128 q rows of one (b,h). Wave owns 64 q (4x16) x its 32-kv half.
// Per-wave partial O/l over its kv half; fp32 combine via LDS at kernel end
// (static softmax -> combine is a pure add). kv tile = 64.
__global__ __launch_bounds__(256, 2) void mqa_attn(const u16* __restrict__ qh,   // [B*S][2048]
                                                   const u16* __restrict__ kh,   // [B*S][128]
                                                   const u16* __restrict__ vhT,  // [128][B*S]
                                                   u16* __restrict__ outp,       // [B*S][2048]
                                                   int S) {
    constexpr float CEXP = 0.08838834764831845f * 1.4426950408889634f;  // scale * log2(e)
    constexpr int KSTR = 136;  // 128 + 8 pad (u16)
    constexpr int VSTR = 72;   // 64 + 8
    constexpr int PSTR = 40;   // 32 + 8
    // carve one arena: sK 8704 u16 | sVT 9216 | sP 4*2560 | sL 256  = 28416 u16 = 56832 B
    __shared__ u16 smem[28416];
    u16* sK = smem;                       // [64][136]
    u16* sVT = smem + 8704;               // [128][72]
    u16* sP = smem + 17920;               // 4 waves x [64][40]
    float* sL = (float*)(smem + 28160);   // [2 qhalf][4 mi][16 c16]
    float* sComb = (float*)smem;          // combine arena (35840 B available, need 32768)

    int t = threadIdx.x, lane = t & 63, wv = t >> 6;
    int quad = lane >> 4, c16 = lane & 15;
    int qhalf = wv >> 1, kvhalf = wv & 1;
    int kvoff = kvhalf * 32;
    int b = blockIdx.z, h = blockIdx.y;
    int q0 = blockIdx.x * 128 + qhalf * 64;
    int BS = b * S;

    // Q fragments (B-operand of S^T mfma): rows q0 + mi*16 + c16
    bf16x8 aq[4][4];
    for (int mi = 0; mi < 4; mi++) {
        const u16* qp = qh + (size_t)(BS + q0 + mi * 16 + c16) * 2048 + h * 128 + quad * 8;
        for (int c = 0; c < 4; c++) aq[mi][c] = *(const bf16x8*)(qp + c * 32);
    }

    f32x4 out[4][8] = {};
    f32x4 lsumv[4] = {};
    u16* sPw = sP + wv * (64 * PSTR);

    // staging coords (256 threads): K 64x128 (4 passes), VT 128x64 (4 passes)
    int kr = t >> 4, kc = (t & 15) * 8;
    int vr = t >> 3, vc = (t & 7) * 8;
    const u16* kbase = kh + (size_t)(BS + kr) * 128 + kc;
    const u16* vbase = vhT + (size_t)vr * 4096 + BS + vc;

    for (int kv0 = 0; kv0 < S; kv0 += 64) {
        __syncthreads();
        for (int ps = 0; ps < 4; ps++)
            *(uint4*)&sK[(kr + ps * 16) * KSTR + kc] =
                *(const uint4*)(kbase + (size_t)(kv0 + ps * 16) * 128);
        for (int ps = 0; ps < 4; ps++)
            *(uint4*)&sVT[(vr + ps * 32) * VSTR + vc] =
                *(const uint4*)(vbase + (size_t)(ps * 32) * 4096 + kv0);
        __syncthreads();

        // scores for this wave's 32-kv half: S^T = K*Q^T (D: row=kv, col=q)
        for (int ni = 0; ni < 2; ni++) {
            f32x4 sc[4] = {};
            for (int c = 0; c < 4; c++) {
                bf16x8 bk = *(const bf16x8*)&sK[(kvoff + ni * 16 + c16) * KSTR + quad * 8 + c * 32];
                for (int mi = 0; mi < 4; mi++)
                    sc[mi] = __builtin_amdgcn_mfma_f32_16x16x32_bf16(bk, aq[mi][c], sc[mi], 0, 0, 0);
            }
            // static softmax; l summed from truncated bf16 so bias cancels in PV/l
            for (int mi = 0; mi < 4; mi++) {
                u32 eu[4];
                f32x4 et;
                for (int p = 0; p < 4; p++) {
                    float e = __builtin_amdgcn_exp2f(sc[mi][p] * CEXP);
                    union { float f; u32 u; } cv; cv.f = e;
                    eu[p] = cv.u;
                    cv.u &= 0xffff0000u;
                    et[p] = cv.f;
                }
                lsumv[mi] += et;
                u32 pk0 = __builtin_amdgcn_perm(eu[1], eu[0], 0x07060302u);
                u32 pk1 = __builtin_amdgcn_perm(eu[3], eu[2], 0x07060302u);
                *(uint2*)&sPw[(mi * 16 + c16) * PSTR + ni * 16 + quad * 4] = make_uint2(pk0, pk1);
            }
        }
        asm volatile("s_waitcnt lgkmcnt(0)" ::: "memory");

        // PV over this wave's kv half: O += P[64 x 32] * V[32 x 128]
        bf16x8 ap[4];
        for (int mi = 0; mi < 4; mi++)
            ap[mi] = *(const bf16x8*)&sPw[(mi * 16 + c16) * PSTR + quad * 8];
        for (int ni = 0; ni < 8; ni++) {
            bf16x8 bv = *(const bf16x8*)&sVT[(ni * 16 + c16) * VSTR + kvoff + quad * 8];
            for (int mi = 0; mi < 4; mi++)
                out[mi][ni] = __builtin_amdgcn_mfma_f32_16x16x32_bf16(ap[mi], bv, out[mi][ni], 0, 0, 0);
        }
    }

    // ---- combine the two kv-halves (pure add: static softmax) ----
    float lp[4];
    for (int mi = 0; mi < 4; mi++) {
        float x = lsumv[mi][0] + lsumv[mi][1] + lsumv[mi][2] + lsumv[mi][3];
        x += __shfl_xor(x, 16, 64);
        x += __shfl_xor(x, 32, 64);  // all lanes: partial l(q = mi*16 + c16)
        lp[mi] = x;
    }
    __syncthreads();  // everyone done with sK/sVT/sP

    if (kvhalf == 1) {
        if (quad == 0)
            for (int mi = 0; mi < 4; mi++) sL[(qhalf * 4 + mi) * 16 + c16] = lp[mi];
        float* dst = sComb + qhalf * 4096;
        for (int mi = 0; mi < 4; mi++)
            for (int j = 0; j < 4; j++)
                *(f32x4*)(dst + (mi * 4 + j) * 256 + lane * 4) = out[mi][j];
    }
    __syncthreads();

    float inv[4][4];
    if (kvhalf == 0) {
        for (int mi = 0; mi < 4; mi++) {
            float ltot = lp[mi] + sL[(qhalf * 4 + mi) * 16 + c16];
            for (int p = 0; p < 4; p++)
                inv[mi][p] = 1.f / __shfl(ltot, quad * 4 + p, 64);
        }
        const float* src = sComb + qhalf * 4096;
        for (int mi = 0; mi < 4; mi++) {
            u16* op = outp + (size_t)(BS + q0 + mi * 16 + quad * 4) * 2048 + h * 128;
            for (int j = 0; j < 4; j++) {
                f32x4 o = out[mi][j] + *(const f32x4*)(src + (mi * 4 + j) * 256 + lane * 4);
                for (int p = 0; p < 4; p++)
                    op[(size_t)p * 2048 + j * 16 + c16] = f2bf(o[p] * inv[mi][p]);
            }
        }
    }
    __syncthreads();

    if (kvhalf == 1) {
        float* dst = sComb + qhalf * 4096;
        for (int mi = 0; mi < 4; mi++)
            for (int j = 4; j < 8; j++)
                *(f32x4*)(dst + (mi * 4 + j - 4) * 256 + lane * 4) = out[mi][j];
    }
    __syncthreads();

    if (kvhalf == 0) {
        const float* src = sComb + qhalf * 4096;
        for (int mi = 0; mi < 4; mi++) {
            u16* op = outp + (size_t)(BS + q0 + mi * 16 + quad * 4) * 2048 + h * 128;
            for (int j = 4; j < 8; j++) {
                f32x4 o = out[mi][j] + *(const f32x4*)(src + (mi * 4 + j - 4) * 256 + lane * 4);
                for (int p = 0; p < 4; p++)
                    op[(size_t)p * 2048 + j * 16 + c16] = f2bf(o[p] * inv[mi][p]);
            }
        }
    }
}

extern "C" void kernel_launch(void* const* d_in, const int* in_sizes, int n_in,
                              void* d_out, int out_size, void* d_ws, size_t ws_size,
                              hipStream_t stream) {
    const float* q  = (const float*)d_in[0];
    const float* k  = (const float*)d_in[1];
    const float* v  = (const float*)d_in[2];
    const float* Wq = (const float*)d_in[3];
    const float* bq = (const float*)d_in[4];
    const float* Wk = (const float*)d_in[5];
    const float* bk = (const float*)d_in[6];
    const float* Wv = (const float*)d_in[7];
    const float* bv = (const float*)d_in[8];
    const float* Wo = (const float*)d_in[9];
    const float* bo = (const float*)d_in[10];
    float* out = (float*)d_out;

    const int S = 2048, D = 2048, Dh = 128, M = 4096;  // M = B*S
    const int QKV = M * D;
    const int WDD = D * D;
    const int WDH = D * Dh;
    const int MDh = M * Dh;

    u16* ws   = (u16*)d_ws;
    u16* q_bf = ws;
    u16* k_bf = q_bf + QKV;
    u16* v_bf = k_bf + QKV;
    u16* WqT  = v_bf + QKV;
    u16* WoT  = WqT + WDD;
    u16* WkT  = WoT + WDD;
    u16* WvT  = WkT + WDH;
    u16* qhb  = WvT + WDH;       // [M][2048] bf16
    u16* khb  = qhb + QKV;       // [M][128]
    u16* vhTb = khb + MDh;       // [128][M]
    u16* aout = vhTb + MDh;      // [M][2048]
    float* kacc = (float*)(aout + QKV);  // [M][128] fp32
    float* vacc = kacc + MDh;            // [M][128] fp32

    hipMemsetAsync(kacc, 0, (size_t)2 * MDh * sizeof(float), stream);

    cvt3<<<dim3(QKV / 1024, 3), 256, 0, stream>>>(q, k, v, q_bf, k_bf, v_bf);
    transpose2<<<dim3(64, 64, 2), 256, 0, stream>>>(Wq, WqT, Wo, WoT, D, D);
    transpose2<<<dim3(64, 4, 2), 256, 0, stream>>>(Wk, WkT, Wv, WvT, D, Dh);

    gemm_bt<u16><<<dim3(32, 16), 256, 0, stream>>>(q_bf, WqT, bq, qhb, M, D, D, D);
    gemm_kv_sk<<<dim3(32, 2, 4), 256, 0, stream>>>(k_bf, v_bf, WkT, WvT, kacc, vacc, D, 512);
    cvt_kv<<<dim3(128, 4, 2), 256, 0, stream>>>(kacc, vacc, bk, bv, khb, vhTb, M);

    mqa_attn<<<dim3(16, 16, 2), 256, 0, stream>>>(qhb, khb, vhTb, aout, S);

    gemm_bt<float><<<dim3(32, 16), 256, 0, stream>>>(aout, WoT, bo, out, M, D, D, D);
}